// Round 3
// baseline (90.400 us; speedup 1.0000x reference)
//
#include <hip/hip_runtime.h>

#define B_  512
#define T_  365
#define C_  10
#define P_  64
#define K_  3650   // T*C
#define K2_ 1825   // K_/2 as float2
#define KP_ 3712   // padded float count (1856 float2), zero-filled tail
#define KP2_ 1856  // KP_/2

// d_out flat offsets (floats), in reference return order
#define OFF_OUT0 0u          // output_seq [B,T,C]
#define OFF_IN   1868800u    // input_seq  [B,T,C]
#define OFF_DIST 3737600u    // distances  [B,P]
#define OFF_IDX  3770368u    // indices    [B]
#define OFF_LAB  3770880u    // label      [B]
#define OFF_MASK 3771392u    // mask       [B,T]

// clang-native 2-float vector: __builtin_nontemporal_store requires a
// native vector type (HIP's float2 class is rejected). Same 8B layout.
typedef float v2f __attribute__((ext_vector_type(2)));

// One block per 2 batch rows; 1024 threads = 16 waves; wave w owns protos
// [4w, 4w+4). Distance in direct masked form:
//   d[b][p] = sum_k (m[k]*x[k] - m[k]*proto[p][k])^2
// (== reference expansion exactly, m binary). LDS holds RAW x (not pre-masked)
// so the input echo can be replayed from LDS at the END of the kernel, after
// the last barrier — removing 8.2 MB of stores from the pre-main-loop
// vmcnt-drain critical path. The mask multiply (u = x*m) moves into the main
// loop (4 extra v_mul/iter, shared across 4 protos) and is bit-exact for
// binary m, so distances/argmin are unchanged vs the previous kernel.
// All large output streams use nontemporal stores so they don't
// write-allocate in L2 and evict the hot 934 KB prototype set that every
// block re-reads (main loop is L2-BW-bound, ~6.5 us model).
__global__ __launch_bounds__(1024) void dist_kernel(
    const float* __restrict__ x, const float* __restrict__ mask,
    const int* __restrict__ label, const float* __restrict__ protos,
    float* __restrict__ out)
{
    __shared__ float xr[2][KP_];    // RAW x rows, zero-padded tail
    __shared__ float mexp[2][KP_];  // mask expanded per-element, zero-padded
    __shared__ float mrow[2][368];  // raw mask rows
    __shared__ float dist[2][64];
    __shared__ int   sel[2];

    const int tid  = threadIdx.x;
    const int lane = tid & 63;
    const int wv   = tid >> 6;      // 0..15
    const int b0   = blockIdx.x * 2;

    // ---- stage mask rows (echo deferred to end) ----
    if (tid < T_) {
        mrow[0][tid] = mask[(size_t)b0 * T_ + tid];
    }
    {
        int t2 = tid - 512;
        if (t2 >= 0 && t2 < T_) {
            mrow[1][t2] = mask[(size_t)(b0 + 1) * T_ + t2];
        }
    }
    __syncthreads();

    // ---- build xr (raw) / mexp with float2 loads; no echo here ----
    for (int i2 = tid; i2 < KP2_; i2 += 1024) {
        const int e0 = 2 * i2;          // K_ is even -> e0 < K_ implies e0+1 < K_
#pragma unroll
        for (int bb = 0; bb < 2; ++bb) {
            float2 xv = make_float2(0.f, 0.f);
            float2 mv = make_float2(0.f, 0.f);
            if (e0 < K_) {
                xv = *(const float2*)(x + (size_t)(b0 + bb) * K_ + e0);
                mv.x = mrow[bb][e0 / C_];
                mv.y = mrow[bb][(e0 + 1) / C_];
            }
            *(float2*)&xr[bb][e0]   = xv;
            *(float2*)&mexp[bb][e0] = mv;
        }
    }
    __syncthreads();

    // ---- main loop: 4 protos x 2 rows per wave, 29 K-steps ----
    const int p0 = wv * 4;
    const float2* pr[4];
#pragma unroll
    for (int q = 0; q < 4; ++q)
        pr[q] = (const float2*)(protos + (size_t)(p0 + q) * K_);
    const float2* xr0 = (const float2*)&xr[0][0];
    const float2* xr1 = (const float2*)&xr[1][0];
    const float2* mr0 = (const float2*)&mexp[0][0];
    const float2* mr1 = (const float2*)&mexp[1][0];

    float acc0[4] = {0.f, 0.f, 0.f, 0.f};
    float acc1[4] = {0.f, 0.f, 0.f, 0.f};

#pragma unroll 4
    for (int it = 0; it < 29; ++it) {
        const int i2  = it * 64 + lane;            // < 1856, LDS is padded
        const int i2c = i2 < K2_ ? i2 : (K2_ - 1); // clamp proto load only
        float2 pv[4];
#pragma unroll
        for (int q = 0; q < 4; ++q) pv[q] = pr[q][i2c];  // 4 indep L2 loads
        const float2 x0 = xr0[i2], m0 = mr0[i2];
        const float2 x1 = xr1[i2], m1 = mr1[i2];
        float2 u0, u1;                              // u = m*x (exact, m binary)
        u0.x = x0.x * m0.x; u0.y = x0.y * m0.y;
        u1.x = x1.x * m1.x; u1.y = x1.y * m1.y;
#pragma unroll
        for (int q = 0; q < 4; ++q) {
            float tx, ty;
            tx = fmaf(-pv[q].x, m0.x, u0.x); acc0[q] = fmaf(tx, tx, acc0[q]);
            ty = fmaf(-pv[q].y, m0.y, u0.y); acc0[q] = fmaf(ty, ty, acc0[q]);
            tx = fmaf(-pv[q].x, m1.x, u1.x); acc1[q] = fmaf(tx, tx, acc1[q]);
            ty = fmaf(-pv[q].y, m1.y, u1.y); acc1[q] = fmaf(ty, ty, acc1[q]);
        }
    }

    // ---- wave reductions, write per-proto distances to LDS ----
#pragma unroll
    for (int q = 0; q < 4; ++q) {
        float v0 = acc0[q], v1 = acc1[q];
        for (int off = 32; off; off >>= 1) {
            v0 += __shfl_down(v0, off);
            v1 += __shfl_down(v1, off);
        }
        if (lane == 0) {
            dist[0][p0 + q] = v0;
            dist[1][p0 + q] = v1;
        }
    }
    __syncthreads();

    // ---- write distances; per-wave argmin (first-occurrence tie-break) ----
    if (tid < 128) {
        int bb = tid >> 6;
        out[OFF_DIST + (size_t)(b0 + bb) * P_ + lane] = dist[bb][lane];
    }
    if (wv < 2) {
        const int bb = wv;
        float v = dist[bb][lane];
        int idx = lane;
        for (int off = 32; off; off >>= 1) {
            float ov = __shfl_down(v, off);
            int   oi = __shfl_down(idx, off);
            if (ov < v || (ov == v && oi < idx)) { v = ov; idx = oi; }
        }
        if (lane == 0) {
            sel[bb] = idx;
            const int b = b0 + bb;
            out[OFF_IDX + b] = (float)idx;
            out[OFF_LAB + b] = (float)label[b];
        }
    }
    __syncthreads();

    // ---- gather selected prototype rows into output_seq (nt stores) ----
#pragma unroll
    for (int bb = 0; bb < 2; ++bb) {
        const v2f* src = (const v2f*)(protos + (size_t)sel[bb] * K_);
        v2f* dst = (v2f*)(out + OFF_OUT0 + (size_t)(b0 + bb) * K_);
        for (int i2 = tid; i2 < K2_; i2 += 1024) {
            v2f v = src[i2];                        // L2-hot proto read
            __builtin_nontemporal_store(v, &dst[i2]);
        }
    }

    // ---- deferred echoes from LDS: input_seq + mask (nt stores) ----
    {
        const v2f* s0 = (const v2f*)&xr[0][0];
        const v2f* s1 = (const v2f*)&xr[1][0];
        v2f* d0 = (v2f*)(out + OFF_IN + (size_t)b0 * K_);
        v2f* d1 = (v2f*)(out + OFF_IN + (size_t)(b0 + 1) * K_);
        for (int i2 = tid; i2 < K2_; i2 += 1024) {
            __builtin_nontemporal_store(s0[i2], &d0[i2]);
            __builtin_nontemporal_store(s1[i2], &d1[i2]);
        }
    }
    if (tid < T_) {
        __builtin_nontemporal_store(mrow[0][tid],
            out + OFF_MASK + (size_t)b0 * T_ + tid);
    }
    {
        int t2 = tid - 512;
        if (t2 >= 0 && t2 < T_) {
            __builtin_nontemporal_store(mrow[1][t2],
                out + OFF_MASK + (size_t)(b0 + 1) * T_ + t2);
        }
    }
}

extern "C" void kernel_launch(void* const* d_in, const int* in_sizes, int n_in,
                              void* d_out, int out_size, void* d_ws, size_t ws_size,
                              hipStream_t stream) {
    const float* x      = (const float*)d_in[0];
    const float* mask   = (const float*)d_in[1];
    const int*   label  = (const int*)d_in[2];
    const float* protos = (const float*)d_in[3];
    float* out = (float*)d_out;

    dist_kernel<<<B_ / 2, 1024, 0, stream>>>(x, mask, label, protos, out);
}

// Round 4
// 88.902 us; speedup vs baseline: 1.0169x; 1.0169x over previous
//
#include <hip/hip_runtime.h>

#define B_  512
#define T_  365
#define C_  10
#define P_  64
#define K_  3650   // T*C
#define K2_ 1825   // K_/2 as float2
#define KP_ 3712   // padded float count (1856 float2), zero-filled tail
#define KP2_ 1856  // KP_/2

// d_out flat offsets (floats), in reference return order
#define OFF_OUT0 0u          // output_seq [B,T,C]
#define OFF_IN   1868800u    // input_seq  [B,T,C]
#define OFF_DIST 3737600u    // distances  [B,P]
#define OFF_IDX  3770368u    // indices    [B]
#define OFF_LAB  3770880u    // label      [B]
#define OFF_MASK 3771392u    // mask       [B,T]

// One block per 2 batch rows; 1024 threads = 16 waves; wave w owns protos
// [4w, 4w+4). Distance in direct masked form:
//   d[b][p] = sum_k (m[k]*x[k] - m[k]*proto[p][k])^2
// (== reference expansion exactly, m binary). LDS holds RAW x (not pre-masked)
// so the input echo replays from LDS at the END of the kernel, after the last
// barrier — keeping 8.2 MB of stores off the pre-main-loop vmcnt-drain path.
// R3 post-mortem: nontemporal stores REGRESSED +1.7us (13.4 MB forced to HBM
// inside the kernel window ~= 2.1us; with cached stores L2 absorbs them at
// ~34 TB/s and drains lazily past end-of-dispatch). All stores are plain
// cached stores here; this isolates the echo-deferral effect.
__global__ __launch_bounds__(1024) void dist_kernel(
    const float* __restrict__ x, const float* __restrict__ mask,
    const int* __restrict__ label, const float* __restrict__ protos,
    float* __restrict__ out)
{
    __shared__ float xr[2][KP_];    // RAW x rows, zero-padded tail
    __shared__ float mexp[2][KP_];  // mask expanded per-element, zero-padded
    __shared__ float mrow[2][368];  // raw mask rows
    __shared__ float dist[2][64];
    __shared__ int   sel[2];

    const int tid  = threadIdx.x;
    const int lane = tid & 63;
    const int wv   = tid >> 6;      // 0..15
    const int b0   = blockIdx.x * 2;

    // ---- stage mask rows (echo deferred to end) ----
    if (tid < T_) {
        mrow[0][tid] = mask[(size_t)b0 * T_ + tid];
    }
    {
        int t2 = tid - 512;
        if (t2 >= 0 && t2 < T_) {
            mrow[1][t2] = mask[(size_t)(b0 + 1) * T_ + t2];
        }
    }
    __syncthreads();

    // ---- build xr (raw) / mexp with float2 loads; no echo here ----
    for (int i2 = tid; i2 < KP2_; i2 += 1024) {
        const int e0 = 2 * i2;          // K_ is even -> e0 < K_ implies e0+1 < K_
#pragma unroll
        for (int bb = 0; bb < 2; ++bb) {
            float2 xv = make_float2(0.f, 0.f);
            float2 mv = make_float2(0.f, 0.f);
            if (e0 < K_) {
                xv = *(const float2*)(x + (size_t)(b0 + bb) * K_ + e0);
                mv.x = mrow[bb][e0 / C_];
                mv.y = mrow[bb][(e0 + 1) / C_];
            }
            *(float2*)&xr[bb][e0]   = xv;
            *(float2*)&mexp[bb][e0] = mv;
        }
    }
    __syncthreads();

    // ---- main loop: 4 protos x 2 rows per wave, 29 K-steps ----
    const int p0 = wv * 4;
    const float2* pr[4];
#pragma unroll
    for (int q = 0; q < 4; ++q)
        pr[q] = (const float2*)(protos + (size_t)(p0 + q) * K_);
    const float2* xr0 = (const float2*)&xr[0][0];
    const float2* xr1 = (const float2*)&xr[1][0];
    const float2* mr0 = (const float2*)&mexp[0][0];
    const float2* mr1 = (const float2*)&mexp[1][0];

    float acc0[4] = {0.f, 0.f, 0.f, 0.f};
    float acc1[4] = {0.f, 0.f, 0.f, 0.f};

#pragma unroll 4
    for (int it = 0; it < 29; ++it) {
        const int i2  = it * 64 + lane;            // < 1856, LDS is padded
        const int i2c = i2 < K2_ ? i2 : (K2_ - 1); // clamp proto load only
        float2 pv[4];
#pragma unroll
        for (int q = 0; q < 4; ++q) pv[q] = pr[q][i2c];  // 4 indep L2 loads
        const float2 x0 = xr0[i2], m0 = mr0[i2];
        const float2 x1 = xr1[i2], m1 = mr1[i2];
        float2 u0, u1;                              // u = m*x (exact, m binary)
        u0.x = x0.x * m0.x; u0.y = x0.y * m0.y;
        u1.x = x1.x * m1.x; u1.y = x1.y * m1.y;
#pragma unroll
        for (int q = 0; q < 4; ++q) {
            float tx, ty;
            tx = fmaf(-pv[q].x, m0.x, u0.x); acc0[q] = fmaf(tx, tx, acc0[q]);
            ty = fmaf(-pv[q].y, m0.y, u0.y); acc0[q] = fmaf(ty, ty, acc0[q]);
            tx = fmaf(-pv[q].x, m1.x, u1.x); acc1[q] = fmaf(tx, tx, acc1[q]);
            ty = fmaf(-pv[q].y, m1.y, u1.y); acc1[q] = fmaf(ty, ty, acc1[q]);
        }
    }

    // ---- wave reductions, write per-proto distances to LDS ----
#pragma unroll
    for (int q = 0; q < 4; ++q) {
        float v0 = acc0[q], v1 = acc1[q];
        for (int off = 32; off; off >>= 1) {
            v0 += __shfl_down(v0, off);
            v1 += __shfl_down(v1, off);
        }
        if (lane == 0) {
            dist[0][p0 + q] = v0;
            dist[1][p0 + q] = v1;
        }
    }
    __syncthreads();

    // ---- write distances; per-wave argmin (first-occurrence tie-break) ----
    if (tid < 128) {
        int bb = tid >> 6;
        out[OFF_DIST + (size_t)(b0 + bb) * P_ + lane] = dist[bb][lane];
    }
    if (wv < 2) {
        const int bb = wv;
        float v = dist[bb][lane];
        int idx = lane;
        for (int off = 32; off; off >>= 1) {
            float ov = __shfl_down(v, off);
            int   oi = __shfl_down(idx, off);
            if (ov < v || (ov == v && oi < idx)) { v = ov; idx = oi; }
        }
        if (lane == 0) {
            sel[bb] = idx;
            const int b = b0 + bb;
            out[OFF_IDX + b] = (float)idx;
            out[OFF_LAB + b] = (float)label[b];
        }
    }
    __syncthreads();

    // ---- gather selected prototype rows into output_seq (cached stores) ----
#pragma unroll
    for (int bb = 0; bb < 2; ++bb) {
        const float2* src = (const float2*)(protos + (size_t)sel[bb] * K_);
        float2* dst = (float2*)(out + OFF_OUT0 + (size_t)(b0 + bb) * K_);
        for (int i2 = tid; i2 < K2_; i2 += 1024) dst[i2] = src[i2];
    }

    // ---- deferred echoes from LDS: input_seq + mask (cached stores) ----
    {
        float2* d0 = (float2*)(out + OFF_IN + (size_t)b0 * K_);
        float2* d1 = (float2*)(out + OFF_IN + (size_t)(b0 + 1) * K_);
        for (int i2 = tid; i2 < K2_; i2 += 1024) {
            d0[i2] = xr0[i2];
            d1[i2] = xr1[i2];
        }
    }
    if (tid < T_) {
        out[OFF_MASK + (size_t)b0 * T_ + tid] = mrow[0][tid];
    }
    {
        int t2 = tid - 512;
        if (t2 >= 0 && t2 < T_) {
            out[OFF_MASK + (size_t)(b0 + 1) * T_ + t2] = mrow[1][t2];
        }
    }
}

extern "C" void kernel_launch(void* const* d_in, const int* in_sizes, int n_in,
                              void* d_out, int out_size, void* d_ws, size_t ws_size,
                              hipStream_t stream) {
    const float* x      = (const float*)d_in[0];
    const float* mask   = (const float*)d_in[1];
    const int*   label  = (const int*)d_in[2];
    const float* protos = (const float*)d_in[3];
    float* out = (float*)d_out;

    dist_kernel<<<B_ / 2, 1024, 0, stream>>>(x, mask, label, protos, out);
}